// Round 14
// baseline (187.451 us; speedup 1.0000x reference)
//
#include <hip/hip_runtime.h>

typedef __attribute__((ext_vector_type(8))) short bf16x8;
typedef __attribute__((ext_vector_type(4))) float f32x4;
typedef __attribute__((ext_vector_type(2))) float f32x2;

__device__ __forceinline__ unsigned short f2bf(float f) {
  unsigned int u = __builtin_bit_cast(unsigned int, f);
  unsigned int r = (u + 0x7FFFu + ((u >> 16) & 1u)) >> 16;  // RNE (finite inputs)
  return (unsigned short)r;
}

// Packed dual-f32 (VOP3P, CDNA4): D = A*B + D / D = A + D on float2 pairs.
// hipcc does not auto-pack scalar fmaf/add pairs -> inline asm.
#define PK_FMA(D, A, B) asm("v_pk_fma_f32 %0, %1, %2, %0" : "+v"(D) : "v"(A), "v"(B))
#define PK_ADD(D, A)    asm("v_pk_add_f32 %0, %1, %0" : "+v"(D) : "v"(A))

// Build bf16 transposed + 16B-chunk-XOR-swizzled weight images in ws.
// wm_img[i]: [col(64)][k(64)] bf16, 128B rows, chunk ^= (col&7); val = Wm[i][k][col]
//            k 0..31 = W_self, k 32..63 = W_nb
// wu_img:    [col(64)][k(128, pad)] bf16, 256B rows, chunk ^= (col&7); k<96: Wu[k][col]
__global__ void prep_weights(const float* __restrict__ Wm,
                             const float* __restrict__ Wu,
                             unsigned short* __restrict__ wm_img,
                             unsigned short* __restrict__ wu_img) {
  const int i = blockIdx.x;
  const int tid = threadIdx.x;
  if (i < 26) {
    for (int e = tid; e < 4096; e += 256) {
      const int col = e & 63, k = e >> 6;
      const float v = Wm[(i * 64 + k) * 64 + col];
      const int bo = col * 128 + (((k >> 3) ^ (col & 7)) << 4) + (k & 7) * 2;
      wm_img[i * 4096 + (bo >> 1)] = f2bf(v);
    }
  } else {
    for (int e = tid; e < 8192; e += 256) {
      const int col = e >> 7, k = e & 127;
      const float v = (k < 96) ? Wu[k * 64 + col] : 0.0f;
      const int bo = col * 256 + (((k >> 3) ^ (col & 7)) << 4) + (k & 7) * 2;
      wu_img[bo >> 1] = f2bf(v);
    }
  }
}

// R14 = R13 (R7 structure + nested-MFMA bias + hoisted staging) + packed-f32
// gate: agg pairs via v_pk_fma_f32 (4 max + 2 pk_fma = 6 instrs vs 8), den via
// v_pk_add_f32. Attacks the post-MFMA dependent VALU tail (the only VALU on
// the per-iteration critical path; R13 showed off-path VALU cuts are neutral).
// Tripwire: WRITE_SIZE == 131072 KB (no spills), VGPR <= 64.
#define CB_STRIDE 10384  // 6*6*18*16 + 16B skew: staging lanes cb=0..3 distinct banks
__global__ __launch_bounds__(512, 4)
void voxconv_main(const float* __restrict__ x,
                  const float* __restrict__ occ,
                  const float* __restrict__ bm,
                  const float* __restrict__ bu,
                  const unsigned short* __restrict__ wm_img,
                  const unsigned short* __restrict__ wu_img,
                  float* __restrict__ out) {
  // x halo: [cb(4)][hx(6)][hy(6)][hz(18)][8ch] bf16 ; strides B: cb CB_STRIDE, hx 1728, hy 288, hz 16
  __shared__ __align__(16) unsigned short x_lds[2 * CB_STRIDE];  // 41536 B
  __shared__ __align__(16) float occ_lds[648];                   // [6][6][18] f32, 2592 B
  __shared__ __align__(16) unsigned short wm_buf[8192];          // 2 x 8KB dbuf; later agg scratch
  // total 60512 B -> LDS_Block_Size 60928 -> 2 blocks/CU

  const int tid  = (int)threadIdx.x;
  const int lane = tid & 63;
  const int w    = tid >> 6;
  const int q    = lane >> 4;   // k-chunk / quarter-wave
  const int m    = lane & 15;   // A row (z) / C col (within 16)
  const int l7   = lane & 7;

  const int id = (int)blockIdx.x;
  const int b  = id >> 10;
  const int ix = (id >> 6) & 15;
  const int iy = (id >> 2) & 15;
  const int iz = id & 3;
  const int x0 = ix << 2, y0 = iy << 2, z0 = iz << 4;

  // ---- stage x halo: per-thread decomposition hoisted (432 active threads,
  // 6 hx-planes; only X varies per plane) ----
  {
    const int scb = tid & 3;          // ch-chunk
    const int sr  = tid >> 2;         // slot within plane (valid < 108)
    const int shz = sr % 18;
    const int shy = sr / 18;
    const bool sact = (sr < 108);
    const int sY = (y0 + 63 + shy) & 63;
    const int sZ = (z0 + 63 + shz) & 63;
    const int sYZ = sY * 64 + sZ;
    const int sldsbase = scb * CB_STRIDE + shy * 288 + shz * 16;
    if (sact) {
      for (int hx = 0; hx < 6; ++hx) {
        const int X = (x0 + 63 + hx) & 63;
        const int vox = (b * 64 + X) * 4096 + sYZ;
        const float4* s4 = (const float4*)(x + vox * 32 + scb * 8);
        const float4 f0 = s4[0];
        const float4 f1 = s4[1];
        uint4 P;
        P.x = (unsigned)f2bf(f0.x) | ((unsigned)f2bf(f0.y) << 16);
        P.y = (unsigned)f2bf(f0.z) | ((unsigned)f2bf(f0.w) << 16);
        P.z = (unsigned)f2bf(f1.x) | ((unsigned)f2bf(f1.y) << 16);
        P.w = (unsigned)f2bf(f1.z) | ((unsigned)f2bf(f1.w) << 16);
        *(uint4*)((char*)x_lds + sldsbase + hx * 1728) = P;
      }
    }
  }
  // ---- stage occ halo (f32) ----
  for (int t = tid; t < 648; t += 512) {
    const int hz = t % 18;
    const int v2 = t / 18;
    const int hy = v2 % 6;
    const int hx = v2 / 6;
    const int X = (x0 + 63 + hx) & 63;
    const int Y = (y0 + 63 + hy) & 63;
    const int Z = (z0 + 63 + hz) & 63;
    occ_lds[t] = occ[((b * 64 + X) * 64 + Y) * 64 + Z];
  }
  // ---- stage first Wm image ----
  ((uint4*)wm_buf)[tid] = ((const uint4*)wm_img)[tid];
  __syncthreads();

  // ---- per-thread constant addresses (wave w owns columns g = 2w, 2w+1) ----
  int aSelf[2], occSelf[2], voxBase[2];
  #pragma unroll
  for (int gg = 0; gg < 2; ++gg) {
    const int g  = w * 2 + gg;
    const int tx = g >> 2, ty = g & 3;
    aSelf[gg]   = q * CB_STRIDE + (tx + 1) * 1728 + (ty + 1) * 288 + (1 + m) * 16;
    occSelf[gg] = (tx + 1) * 108 + (ty + 1) * 18 + 1 + q * 4;
    voxBase[gg] = ((b * 64 + (x0 + tx)) * 64 + (y0 + ty)) * 64 + z0;
  }
  int bOffS[4], bOffN[4], colIdx[4];
  #pragma unroll
  for (int tt = 0; tt < 4; ++tt) {
    const int col = tt * 16 + m;
    colIdx[tt] = col;
    bOffS[tt] = col * 128 + ((q ^ l7) << 4);          // k chunk q   (self, k 0..31)
    bOffN[tt] = col * 128 + (((4 + q) ^ l7) << 4);    // k chunk 4+q (nb,  k 32..63)
  }

  // Loop-invariant self A-fragments (x_lds immutable after prologue);
  // also reused as the epilogue's x fragment.
  bf16x8 aS[2];
  #pragma unroll
  for (int gg = 0; gg < 2; ++gg)
    aS[gg] = *(const bf16x8*)((const char*)x_lds + aSelf[gg]);

  // agg/den as packed f32 pairs: [gg][tt][pair] / [gg][pair], pair p = {j=2p, j=2p+1}
  f32x2 agg2[2][4][2];
  f32x2 den2[2][2];
  #pragma unroll
  for (int gg = 0; gg < 2; ++gg) {
    #pragma unroll
    for (int p = 0; p < 2; ++p) {
      den2[gg][p] = (f32x2){0.0f, 0.0f};
      #pragma unroll
      for (int tt = 0; tt < 4; ++tt) agg2[gg][tt][p] = (f32x2){0.0f, 0.0f};
    }
  }

  // Per-wave async-prefetch addresses: wave w's 1KB slice of the 8KB image.
  const unsigned short* gsrc_base = wm_img + 4096 + (unsigned)tid * 8;  // image i+1 at i=0

  // ---- 26-offset main loop, Wm double-buffered via global_load_lds ----
  int cur = 0;
  #pragma unroll 1
  for (int i = 0; i < 26; ++i) {
    if (i < 25) {
      // async global->LDS: 16B/lane, wave-uniform LDS base (w*1024 slice)
      __builtin_amdgcn_global_load_lds(
          (const __attribute__((address_space(1))) void*)(gsrc_base + (unsigned)i * 4096),
          (__attribute__((address_space(3))) void*)((char*)wm_buf + (cur ^ 1) * 8192 + w * 1024 + (lane * 16)),
          16, 0, 0);
    }

    // bm row i from global: 6.6KB L2-resident table
    float bmv[4];
    #pragma unroll
    for (int tt = 0; tt < 4; ++tt) bmv[tt] = bm[i * 64 + colIdx[tt]];

    const int oi  = (i < 13) ? i : i + 1;          // skip (0,0,0)
    const int dxo = oi / 9 - 1;
    const int dyo = (oi / 3) % 3 - 1;
    const int dzo = oi % 3 - 1;
    // neighbor q = p - d  (roll semantics: x_nb[p] = x[p-d])
    const int dA = -(dxo * 1728 + dyo * 288 + dzo * 16);
    const int dO = -(dxo * 108 + dyo * 18 + dzo);

    // neighbor A-frags + occ pairs for both columns (shared across all tt)
    bf16x8 aN[2];
    f32x2 on2[2][2];
    #pragma unroll
    for (int gg = 0; gg < 2; ++gg) {
      aN[gg] = *(const bf16x8*)((const char*)x_lds + aSelf[gg] + dA);
      const int ob = occSelf[gg] + dO;
      on2[gg][0] = (f32x2){occ_lds[ob],     occ_lds[ob + 1]};
      on2[gg][1] = (f32x2){occ_lds[ob + 2], occ_lds[ob + 3]};
    }

    const char* wmc = (const char*)wm_buf + cur * 8192;
    // B-frags per-tt (live 8 regs, shared by both columns' MFMAs); nested
    // MFMA pair with C = bmq broadcast (shared by both gg; D != C).
    #pragma unroll
    for (int tt = 0; tt < 4; ++tt) {
      const bf16x8 bS = *(const bf16x8*)(wmc + bOffS[tt]);
      const bf16x8 bN = *(const bf16x8*)(wmc + bOffN[tt]);
      const f32x4 bmq = {bmv[tt], bmv[tt], bmv[tt], bmv[tt]};
      #pragma unroll
      for (int gg = 0; gg < 2; ++gg) {
        const f32x4 acc = __builtin_amdgcn_mfma_f32_16x16x32_bf16(
            aN[gg], bN,
            __builtin_amdgcn_mfma_f32_16x16x32_bf16(aS[gg], bS, bmq, 0, 0, 0),
            0, 0, 0);
        // gated accumulate: 4 v_max + 2 v_pk_fma (vs 4 max + 4 fma scalar)
        f32x2 ms0, ms1;
        ms0.x = fmaxf(acc[0], 0.0f);
        ms0.y = fmaxf(acc[1], 0.0f);
        ms1.x = fmaxf(acc[2], 0.0f);
        ms1.y = fmaxf(acc[3], 0.0f);
        PK_FMA(agg2[gg][tt][0], ms0, on2[gg][0]);
        PK_FMA(agg2[gg][tt][1], ms1, on2[gg][1]);
      }
    }
    #pragma unroll
    for (int gg = 0; gg < 2; ++gg) {
      PK_ADD(den2[gg][0], on2[gg][0]);
      PK_ADD(den2[gg][1], on2[gg][1]);
    }

    // barrier drains vmcnt(0) -> prefetched image i+1 is resident in cur^1
    __syncthreads();
    cur ^= 1;
  }

  // ---- agg /= (den + 1e-8) ----
  #pragma unroll
  for (int gg = 0; gg < 2; ++gg)
    #pragma unroll
    for (int p = 0; p < 2; ++p) {
      f32x2 r;
      r.x = 1.0f / (den2[gg][p].x + 1e-8f);
      r.y = 1.0f / (den2[gg][p].y + 1e-8f);
      #pragma unroll
      for (int tt = 0; tt < 4; ++tt) {
        agg2[gg][tt][p].x *= r.x;
        agg2[gg][tt][p].y *= r.y;
      }
    }

  // ---- update matmul: out = ([x|agg] @ Wu + bu) * occ_self ----
  char* scratch = (char*)wm_buf + w * 2048;  // per-wave 16 rows x 128B (aliases dbuf; private per wave)
  f32x4 buq[4];
  #pragma unroll
  for (int tt = 0; tt < 4; ++tt) {
    const float bv = bu[colIdx[tt]];
    buq[tt] = (f32x4){bv, bv, bv, bv};
  }

  #pragma unroll
  for (int gg = 0; gg < 2; ++gg) {
    // C-layout agg -> bf16 A-layout scratch (row-XOR swizzle); per-wave private,
    // wave-synchronous: no barrier needed (DS ops complete in order per wave)
    #pragma unroll
    for (int tt = 0; tt < 4; ++tt) {
      const int colhi = tt * 2 + ((lane >> 3) & 1);  // col>>3
      #pragma unroll
      for (int j = 0; j < 4; ++j) {
        const int row = q * 4 + j;
        const int bo = row * 128 + ((colhi ^ (row & 7)) << 4) + l7 * 2;
        const float v = (j & 1) ? agg2[gg][tt][j >> 1].y : agg2[gg][tt][j >> 1].x;
        *(unsigned short*)(scratch + bo) = f2bf(v);
      }
    }
    const bf16x8 ag0 = *(const bf16x8*)(scratch + m * 128 + ((q ^ (m & 7)) << 4));
    const bf16x8 ag1 = *(const bf16x8*)(scratch + m * 128 + (((4 + q) ^ (m & 7)) << 4));
    float os[4];
    #pragma unroll
    for (int j = 0; j < 4; ++j) os[j] = occ_lds[occSelf[gg] + j];
    // Wu fragments per-tt from global (L2-resident 16KB image); nested chain
    // with C = buq[tt] (shared across gg)
    #pragma unroll
    for (int tt = 0; tt < 4; ++tt) {
      const char* wc = (const char*)wu_img + colIdx[tt] * 256;
      const bf16x8 bux  = *(const bf16x8*)(wc + ((q ^ l7) << 4));        // Wu k 0..31 (x)
      const bf16x8 bua0 = *(const bf16x8*)(wc + (((4 + q) ^ l7) << 4));  // Wu k 32..63
      const bf16x8 bua1 = *(const bf16x8*)(wc + (((8 + q) ^ l7) << 4));  // Wu k 64..95
      const f32x4 acc = __builtin_amdgcn_mfma_f32_16x16x32_bf16(
          ag1, bua1,
          __builtin_amdgcn_mfma_f32_16x16x32_bf16(
              ag0, bua0,
              __builtin_amdgcn_mfma_f32_16x16x32_bf16(aS[gg], bux, buq[tt], 0, 0, 0),
              0, 0, 0),
          0, 0, 0);
      #pragma unroll
      for (int j = 0; j < 4; ++j) {
        out[(voxBase[gg] + q * 4 + j) * 64 + colIdx[tt]] = acc[j] * os[j];
      }
    }
  }
}

extern "C" void kernel_launch(void* const* d_in, const int* in_sizes, int n_in,
                              void* d_out, int out_size, void* d_ws, size_t ws_size,
                              hipStream_t stream) {
  const float* x   = (const float*)d_in[0];
  const float* occ = (const float*)d_in[1];
  const float* Wm  = (const float*)d_in[2];
  const float* bm  = (const float*)d_in[3];
  const float* Wu  = (const float*)d_in[4];
  const float* bu  = (const float*)d_in[5];
  float* out = (float*)d_out;

  unsigned short* wm_img = (unsigned short*)d_ws;        // 26*4096 ushort = 208 KB
  unsigned short* wu_img = wm_img + 26 * 4096;           // 8192 ushort   =  16 KB

  prep_weights<<<27, 256, 0, stream>>>(Wm, Wu, wm_img, wu_img);
  voxconv_main<<<2048, 512, 0, stream>>>(x, occ, bm, bu, wm_img, wu_img, out);
}